// Round 5
// baseline (15498.395 us; speedup 1.0000x reference)
//
#include <hip/hip_runtime.h>
#include <math.h>

#define BB 16
#define LL 64
#define TT 63          // L-1 steps
#define HH 512
#define AA 32          // ATTN window
#define VV 32000
#define NCHUNK 1000    // V chunks for big matmul
#define CHW 32         // cols per chunk (1000*32 = 32000)
#define PAD_TOK 1
#define SOS_TOK 2
#define HSROW 96       // A + L rows in hs_buf
#define ZK 1536        // z length
#define FLTMAX 3.402823466e38f

__device__ __forceinline__ float sigm(float x){ return 1.0f/(1.0f + __expf(-x)); }

// ---------------- prologue: xwpre[t][b][:] = b_ctx + emb[tok(t,b)] @ W_ctx[0:512] ----------------
// (identical to rounds 3/4)
__global__ __launch_bounds__(256) void k_pre(const int* __restrict__ s, const float* __restrict__ emb,
                      const float* __restrict__ Wctx, const float* __restrict__ bctx,
                      float* __restrict__ xwpre)
{
    int t = blockIdx.x >> 3;          // 0..62
    int jc = blockIdx.x & 7;          // 0..7
    int tid = threadIdx.x;
    int jj = tid & 63, bq = tid >> 6; // bq 0..3
    int j = jc*64 + jj;
    __shared__ int toks[BB];
    __shared__ float xs[BB][HH];
    if (tid < BB) {
        int b = tid;
        toks[b] = (t == 0) ? SOS_TOK : s[b*LL + (t-1)];
    }
    __syncthreads();
    for (int i = tid; i < BB*HH; i += 256) {
        int b = i >> 9, k = i & 511;
        xs[b][k] = emb[(size_t)toks[b]*HH + k];
    }
    __syncthreads();
    float acc[4];
    #pragma unroll
    for (int u = 0; u < 4; u++) acc[u] = bctx[j];
    for (int k = 0; k < HH; k += 4) {
        float w0 = Wctx[(k+0)*HH+j], w1 = Wctx[(k+1)*HH+j],
              w2 = Wctx[(k+2)*HH+j], w3 = Wctx[(k+3)*HH+j];
        #pragma unroll
        for (int u = 0; u < 4; u++) {
            int b = bq*4 + u;
            float4 hv = *reinterpret_cast<const float4*>(&xs[b][k]);
            acc[u] = fmaf(hv.x, w0, acc[u]);
            acc[u] = fmaf(hv.y, w1, acc[u]);
            acc[u] = fmaf(hv.z, w2, acc[u]);
            acc[u] = fmaf(hv.w, w3, acc[u]);
        }
    }
    #pragma unroll
    for (int u = 0; u < 4; u++) {
        int b = bq*4 + u;
        xwpre[((size_t)t*BB + b)*HH + j] = acc[u];
    }
}

// ---------------- step-finish: replicate fp32 log_softmax + s*logp quantization ----------------
// (identical to rounds 2-4 except the pmax pre-fold for NCHUNK=1000; gmax is a pure max -> bit-safe)
__device__ void finish_step(int tp, int b, int tid,
                            const int* __restrict__ s,
                            const float* __restrict__ lb,
                            const float* __restrict__ pmax,
                            const float* __restrict__ spart,
                            const float* __restrict__ bsw,
                            float* __restrict__ nll, float* __restrict__ out,
                            float* cv, int* ci, double* sdd, float* extra)
{
    // gmax over 1000 chunk maxes (512 threads, one guarded pre-fold)
    float v = pmax[tid*BB + b];
    if (tid + 512 < NCHUNK) v = fmaxf(v, pmax[(tid+512)*BB + b]);
    cv[tid] = v; __syncthreads();
    for (int sft = 256; sft >= 1; sft >>= 1) {
        if (tid < sft) cv[tid] = fmaxf(cv[tid], cv[tid+sft]);
        __syncthreads();
    }
    float gmax = cv[0];
    __syncthreads();

    // pass A: S = sum exp(fl32(x - gmax)), fp64 Taylor (|u| small; bias-free)
    const float* Lb = lb + (size_t)b*VV;
    double sd = 0.0;
    for (int col = tid; col < VV; col += 512) {
        float d1 = Lb[col] - gmax;
        double u = (double)d1, e;
        if (u < -0.25) {
            e = exp(u);
        } else {
            e = 1.0 + u*(1.0/7.0);
            e = 1.0 + u*e*(1.0/6.0);
            e = 1.0 + u*e*(1.0/5.0);
            e = 1.0 + u*e*(1.0/4.0);
            e = 1.0 + u*e*(1.0/3.0);
            e = 1.0 + u*e*(1.0/2.0);
            e = 1.0 + u*e;
        }
        sd += e;
    }
    sdd[tid] = sd; __syncthreads();
    for (int sft = 256; sft >= 1; sft >>= 1) {
        if (tid < sft) sdd[tid] += sdd[tid+sft];
        __syncthreads();
    }
    float logS = logf((float)sdd[0]);

    // switch s = sigmoid(z), precise expf (replicates np's 1/(1+exp(-z)))
    float z = bsw[0];
    #pragma unroll
    for (int i2 = 0; i2 < 8; i2++) z += spart[b*8 + i2];
    float sF = 1.0f/(1.0f + expf(-z));
    __syncthreads();

    // pass B: quantized argmax + target capture
    int tg = s[b*LL + tp + 1];
    float best = -FLTMAX; int bidx = 0x7fffffff;
    for (int col = tid; col < VV; col += 512) {
        float d1 = Lb[col] - gmax;
        float d2 = d1 - logS;
        float pq = sF * d2;
        if (pq > best) { best = pq; bidx = col; }
        if (col == tg) extra[0] = pq;
    }
    cv[tid] = best; ci[tid] = bidx; __syncthreads();
    for (int sft = 256; sft >= 1; sft >>= 1) {
        if (tid < sft) {
            float v2 = cv[tid+sft]; int i2 = ci[tid+sft];
            if (v2 > cv[tid] || (v2 == cv[tid] && i2 < ci[tid])) { cv[tid] = v2; ci[tid] = i2; }
        }
        __syncthreads();
    }
    if (tid == 0) {
        out[1 + b*TT + tp] = (float)ci[0];
        nll[tp*BB + b] = (tg != PAD_TOK) ? -extra[0] : 0.f;
    }
    __syncthreads();
}

// ---------------- per-step: q = h_prev @ W_hid + b_hid (128 blocks x 64) ----------------
// Same fmaf chain as the old k_attn phase 2; h_prev reads are wave-uniform -> scalar loads.
__global__ __launch_bounds__(64) void k_q(
    int t, const float* __restrict__ Whid, const float* __restrict__ bhid,
    const float* __restrict__ hs, float* __restrict__ qg)
{
    int b = blockIdx.x >> 3, jc = blockIdx.x & 7;
    int j = jc*64 + threadIdx.x;
    const float* hp = hs + ((size_t)b*HSROW + (AA + t - 1))*HH;
    float acc = bhid[j];
    #pragma unroll 8
    for (int k = 0; k < HH; k += 4) {
        float4 hv = *reinterpret_cast<const float4*>(&hp[k]);
        acc = fmaf(hv.x, Whid[(k+0)*HH+j], acc);
        acc = fmaf(hv.y, Whid[(k+1)*HH+j], acc);
        acc = fmaf(hv.z, Whid[(k+2)*HH+j], acc);
        acc = fmaf(hv.w, Whid[(k+3)*HH+j], acc);
    }
    qg[b*HH + j] = acc;
}

// ---------------- per-step: hid = selu(xwpre + ctx @ W_ctx[512:1024]) (128 blocks x 64) ----------------
__global__ __launch_bounds__(64) void k_hid(
    int t, const float* __restrict__ Wctx, const float* __restrict__ xwpre,
    const float* __restrict__ ctxg, float* __restrict__ hidg)
{
    int b = blockIdx.x >> 3, jc = blockIdx.x & 7;
    int j = jc*64 + threadIdx.x;
    float acc = xwpre[((size_t)t*BB + b)*HH + j];
    const float* W2 = Wctx + (size_t)HH*HH;
    const float* cx = ctxg + b*HH;
    #pragma unroll 8
    for (int k = 0; k < HH; k += 4) {
        float4 hv = *reinterpret_cast<const float4*>(&cx[k]);
        acc = fmaf(hv.x, W2[(k+0)*HH+j], acc);
        acc = fmaf(hv.y, W2[(k+1)*HH+j], acc);
        acc = fmaf(hv.z, W2[(k+2)*HH+j], acc);
        acc = fmaf(hv.w, W2[(k+3)*HH+j], acc);
    }
    const float scl = 1.0507009873554805f, al = 1.6732632423543772f;
    hidg[b*HH + j] = (acc > 0.f) ? scl*acc : scl*al*expm1f(acc);
}

// ---------------- per-step kernel: finish prev step + scores + softmax + context ----------------
__global__ __launch_bounds__(512) void k_attn(
    int t, const int* __restrict__ s,
    const float* __restrict__ vw, const float* __restrict__ vb,
    const float* __restrict__ qg,
    const float* __restrict__ hs, float* __restrict__ ctxg,
    const float* __restrict__ lb, const float* __restrict__ pmax,
    const float* __restrict__ spart, const float* __restrict__ bsw,
    float* __restrict__ nll, float* __restrict__ out)
{
    int b = blockIdx.x, tid = threadIdx.x;
    __shared__ float qs[HH];
    __shared__ float sc[AA], at[AA];
    __shared__ float cv[512];
    __shared__ int   ci[512];
    __shared__ double sdd[512];
    __shared__ float extra[2];

    // ---- phase 0: finish step t-1 ----
    if (t > 0) {
        finish_step(t-1, b, tid, s, lb, pmax, spart, bsw, nll, out, cv, ci, sdd, extra);
    }

    // ---- load q (same values as old in-block phase 2) ----
    for (int k = tid; k < HH; k += 512) qs[k] = qg[b*HH + k];
    __syncthreads();

    // ---- phase 3: scores[a] = tanh(q + mem[a]) . v_w + v_b (masked) ----
    {
        int w = tid >> 6, lane = tid & 63;
        for (int r = 0; r < 4; r++) {
            int a = w + 8*r;
            const float* mem = hs + ((size_t)b*HSROW + (t + a))*HH;
            float p = 0.f;
            for (int j = lane; j < HH; j += 64) p += tanhf(qs[j] + mem[j]) * vw[j];
            for (int m = 32; m >= 1; m >>= 1) p += __shfl_xor(p, m);
            if (lane == 0) sc[a] = (a >= AA - t) ? (p + vb[0]) : -1e20f;
        }
    }
    __syncthreads();

    // ---- phase 4: softmax over 32 (wave 0) ----
    if (tid < 64) {
        float v = (tid < 32) ? sc[tid] : -FLTMAX;
        float m = v;
        for (int sh = 16; sh >= 1; sh >>= 1) m = fmaxf(m, __shfl_xor(m, sh));
        float e = (tid < 32) ? __expf(v - m) : 0.f;
        float ss = e;
        for (int sh = 16; sh >= 1; sh >>= 1) ss += __shfl_xor(ss, sh);
        if (tid < 32) at[tid] = e / ss;
    }
    __syncthreads();

    // ---- phase 5: context -> global ----
    {
        int j = tid;
        float ctx = 0.f;
        for (int a = 0; a < AA; a++)
            ctx += at[a] * hs[((size_t)b*HSROW + (t + a))*HH + j];
        ctxg[b*HH + j] = ctx;
    }
}

// ---------------- per-step kernel 2: gates + h_new/c_new + hs_buf write + zbuf fill ----------------
// (identical to round 4)
__global__ __launch_bounds__(256) void k_gates(
    int t, const int* __restrict__ parents,
    const float* __restrict__ Wih, const float* __restrict__ Whh,
    const float* __restrict__ blstm, const float* __restrict__ wsw,
    const float* __restrict__ hidg, float* __restrict__ hs,
    float* __restrict__ cvec, float* __restrict__ spart,
    float* __restrict__ zbuf)
{
    int bid = blockIdx.x, b = bid >> 3, hc = bid & 7, h0 = hc*64;
    int tid = threadIdx.x, g = tid >> 6, jj = tid & 63, j = h0 + jj, col = g*HH + j;
    __shared__ float hid_s[HH], h_s[HH];
    __shared__ float gsl[4][64];
    const float* hp = hs + ((size_t)b*HSROW + (AA + t - 1))*HH;
    for (int k = tid; k < HH; k += 256) { hid_s[k] = hidg[b*HH + k]; h_s[k] = hp[k]; }
    __syncthreads();
    float acc = blstm[col];
    for (int k = 0; k < HH; k += 4) {
        float4 hv = *reinterpret_cast<const float4*>(&hid_s[k]);
        acc = fmaf(hv.x, Wih[(size_t)(k+0)*2048 + col], acc);
        acc = fmaf(hv.y, Wih[(size_t)(k+1)*2048 + col], acc);
        acc = fmaf(hv.z, Wih[(size_t)(k+2)*2048 + col], acc);
        acc = fmaf(hv.w, Wih[(size_t)(k+3)*2048 + col], acc);
    }
    for (int k = 0; k < HH; k += 4) {
        float4 hv = *reinterpret_cast<const float4*>(&h_s[k]);
        acc = fmaf(hv.x, Whh[(size_t)(k+0)*2048 + col], acc);
        acc = fmaf(hv.y, Whh[(size_t)(k+1)*2048 + col], acc);
        acc = fmaf(hv.z, Whh[(size_t)(k+2)*2048 + col], acc);
        acc = fmaf(hv.w, Whh[(size_t)(k+3)*2048 + col], acc);
    }
    gsl[g][jj] = acc;
    __syncthreads();
    // h_par slice copy into zbuf (pre-update rows only: p <= t-1, and t==0 -> zeros)
    if (tid >= 64 && tid < 128) {
        int jj2 = tid - 64;
        int par = parents[t];
        int tm1 = (t - 1 > 0) ? (t - 1) : 0;
        int p = (par < 0) ? 0 : ((par > tm1) ? tm1 : par);
        float v = (t == 0) ? 0.f : hs[((size_t)b*HSROW + (AA + p))*HH + h0 + jj2];
        zbuf[(size_t)b*ZK + 2*HH + h0 + jj2] = v;
    }
    if (tid < 64) {
        float gi = gsl[0][jj], gf = gsl[1][jj], gg = gsl[2][jj], go = gsl[3][jj];
        float cp = cvec[b*HH + j];
        float cn = sigm(gf)*cp + sigm(gi)*tanhf(gg);
        float hn = sigm(go)*tanhf(cn);
        cvec[b*HH + j] = cn;
        hs[((size_t)b*HSROW + (AA + t))*HH + j] = hn;
        zbuf[(size_t)b*ZK + j] = hn;
        zbuf[(size_t)b*ZK + HH + j] = cn;
        float sp = hn*wsw[j] + cn*wsw[HH + j];
        for (int m = 32; m >= 1; m >>= 1) sp += __shfl_xor(sp, m);
        if (jj == 0) spart[b*8 + hc] = sp;
    }
}

// ---------------- per-step kernel 3: streaming GEMV logits ----------------
// 1000 blocks x 512 threads: cl=tid&31 (32 cols), kh=(tid>>5)&1, b0=(tid>>6)*2 (2 acc chains).
// 8000 waves -> 32 waves/CU. No LDS, no barriers; kh-combine via shfl_xor(.,32) in accA+accB
// order; per-(col,b,kh) fmaf chains bit-identical to rounds 2-4.
__global__ __launch_bounds__(512) void k_logits(
    const float* __restrict__ Wg, const float* __restrict__ bg,
    const float* __restrict__ zbuf,
    float* __restrict__ lb, float* __restrict__ pmax)
{
    int bid = blockIdx.x, tid = threadIdx.x;
    int cl = tid & 31;
    int kh = (tid >> 5) & 1;
    int b0 = (tid >> 6) * 2;
    int col = bid * CHW + cl;

    float acc[2];
    float binit = (kh == 0) ? bg[col] : 0.f;
    acc[0] = binit; acc[1] = binit;

    for (int kc = 0; kc < 3; kc++) {
        const float* wbase = Wg + (size_t)(kc*512)*VV + col;
        const float* zb = zbuf + kc*512;
        #pragma unroll 4
        for (int k4 = 0; k4 < 64; k4++) {
            int kb = kh*256 + k4*4;
            const float* wr = wbase + (size_t)kb*VV;
            float w0 = wr[0], w1 = wr[VV], w2 = wr[2*VV], w3 = wr[3*VV];
            #pragma unroll
            for (int u = 0; u < 2; u++) {
                float4 z = *reinterpret_cast<const float4*>(&zb[(size_t)(b0+u)*ZK + kb]);
                acc[u] = fmaf(z.x, w0, fmaf(z.y, w1, fmaf(z.z, w2, fmaf(z.w, w3, acc[u]))));
            }
        }
    }

    // kh combine: partner lane (tid^32) holds the other half's partial for the same (col,b)
    float oth0 = __shfl_xor(acc[0], 32);
    float oth1 = __shfl_xor(acc[1], 32);
    if (kh == 0) {
        float tot0 = acc[0] + oth0;     // accA + accB, same order as rounds 2-4
        float tot1 = acc[1] + oth1;
        lb[(size_t)(b0 + 0)*VV + col] = tot0;
        lb[(size_t)(b0 + 1)*VV + col] = tot1;
        // block max over the 32 cols (lanes 0-31 of this wave)
        float v0 = tot0, v1 = tot1;
        for (int m = 16; m >= 1; m >>= 1) {
            v0 = fmaxf(v0, __shfl_xor(v0, m));
            v1 = fmaxf(v1, __shfl_xor(v1, m));
        }
        if ((tid & 63) == 0) {
            pmax[bid*BB + b0 + 0] = v0;
            pmax[bid*BB + b0 + 1] = v1;
        }
    }
}

// ---------------- finish last step (tp = TT-1), 16 blocks ----------------
__global__ __launch_bounds__(512) void k_fin_last(
    const int* __restrict__ s,
    const float* __restrict__ lb, const float* __restrict__ pmax,
    const float* __restrict__ spart, const float* __restrict__ bsw,
    float* __restrict__ nll, float* __restrict__ out)
{
    __shared__ float cv[512];
    __shared__ int   ci[512];
    __shared__ double sdd[512];
    __shared__ float extra[2];
    finish_step(TT-1, blockIdx.x, threadIdx.x, s, lb, pmax, spart, bsw, nll, out, cv, ci, sdd, extra);
}

// ---------------- loss ----------------
__global__ __launch_bounds__(256) void k_final_loss(
    const float* __restrict__ nll, float* __restrict__ out)
{
    __shared__ double cs2[256];
    int tid = threadIdx.x;
    double psm = 0.0;
    for (int i = tid; i < TT*BB; i += 256) psm += (double)nll[i];
    cs2[tid] = psm; __syncthreads();
    for (int sft = 128; sft >= 1; sft >>= 1) {
        if (tid < sft) cs2[tid] += cs2[tid+sft];
        __syncthreads();
    }
    if (tid == 0) out[0] = (float)(cs2[0] / (double)BB);
}

extern "C" void kernel_launch(void* const* d_in, const int* in_sizes, int n_in,
                              void* d_out, int out_size, void* d_ws, size_t ws_size,
                              hipStream_t stream)
{
    const int*   s_tok = (const int*)  d_in[0];
    const int*   par   = (const int*)  d_in[1];
    const float* emb   = (const float*)d_in[2];
    const float* Whid  = (const float*)d_in[3];
    const float* bhid  = (const float*)d_in[4];
    const float* vw    = (const float*)d_in[5];
    const float* vb    = (const float*)d_in[6];
    const float* Wctx  = (const float*)d_in[7];
    const float* bctx  = (const float*)d_in[8];
    const float* Wih   = (const float*)d_in[9];
    const float* Whh   = (const float*)d_in[10];
    const float* blstm = (const float*)d_in[11];
    const float* Wg    = (const float*)d_in[12];
    const float* bg    = (const float*)d_in[13];
    const float* wsw   = (const float*)d_in[14];
    const float* bsw   = (const float*)d_in[15];
    float* out = (float*)d_out;

    float* ws    = (float*)d_ws;
    float* hs    = ws;                     // 16*96*512 = 786432
    float* cvec  = hs    + 786432;         // 8192
    float* xwpre = cvec  + 8192;           // 63*16*512 = 516096
    float* hidg  = xwpre + 516096;         // 8192
    float* qg    = hidg  + 8192;           // 8192
    float* ctxg  = qg    + 8192;           // 8192
    float* pmax  = ctxg  + 8192;           // 16000
    float* spart = pmax  + 16000;          // 128
    float* nll   = spart + 128;            // 1008
    float* lb    = nll   + 1008;           // 16*32000 = 512000
    float* zbuf  = lb    + 512000;         // 16*1536 = 24576

    // zero hs_buf + cvec (adjacent)
    hipMemsetAsync(hs, 0, (786432 + 8192) * sizeof(float), stream);

    hipLaunchKernelGGL(k_pre, dim3(TT*8), dim3(256), 0, stream, s_tok, emb, Wctx, bctx, xwpre);

    for (int t = 0; t < TT; t++) {
        hipLaunchKernelGGL(k_q, dim3(128), dim3(64), 0, stream,
            t, Whid, bhid, hs, qg);
        hipLaunchKernelGGL(k_attn, dim3(BB), dim3(512), 0, stream,
            t, s_tok, vw, vb, qg, hs, ctxg,
            lb, pmax, spart, bsw, nll, out);
        hipLaunchKernelGGL(k_hid, dim3(128), dim3(64), 0, stream,
            t, Wctx, xwpre, ctxg, hidg);
        hipLaunchKernelGGL(k_gates, dim3(128), dim3(256), 0, stream,
            t, par, Wih, Whh, blstm, wsw, hidg, hs, cvec, spart, zbuf);
        hipLaunchKernelGGL(k_logits, dim3(NCHUNK), dim3(512), 0, stream,
            Wg, bg, zbuf, lb, pmax);
    }

    hipLaunchKernelGGL(k_fin_last, dim3(BB), dim3(512), 0, stream,
        s_tok, lb, pmax, spart, bsw, nll, out);
    hipLaunchKernelGGL(k_final_loss, dim3(1), dim3(256), 0, stream, nll, out);
}

// Round 6
// 9752.062 us; speedup vs baseline: 1.5892x; 1.5892x over previous
//
#include <hip/hip_runtime.h>
#include <math.h>

#define BB 16
#define LL 64
#define TT 63          // L-1 steps
#define HH 512
#define AA 32          // ATTN window
#define VV 32000
#define NCHUNK 500     // V chunks for big matmul
#define CHW 64         // cols per chunk (500*64 = 32000)
#define PAD_TOK 1
#define SOS_TOK 2
#define HSROW 96       // A + L rows in hs_buf
#define ZK 1536        // z length
#define FLTMAX 3.402823466e38f

__device__ __forceinline__ float sigm(float x){ return 1.0f/(1.0f + __expf(-x)); }

// ---------------- prologue: xwpre[t][b][:] = b_ctx + emb[tok(t,b)] @ W_ctx[0:512] ----------------
__global__ __launch_bounds__(256) void k_pre(const int* __restrict__ s, const float* __restrict__ emb,
                      const float* __restrict__ Wctx, const float* __restrict__ bctx,
                      float* __restrict__ xwpre)
{
    int t = blockIdx.x >> 3;          // 0..62
    int jc = blockIdx.x & 7;          // 0..7
    int tid = threadIdx.x;
    int jj = tid & 63, bq = tid >> 6; // bq 0..3
    int j = jc*64 + jj;
    __shared__ int toks[BB];
    __shared__ float xs[BB][HH];
    if (tid < BB) {
        int b = tid;
        toks[b] = (t == 0) ? SOS_TOK : s[b*LL + (t-1)];
    }
    __syncthreads();
    for (int i = tid; i < BB*HH; i += 256) {
        int b = i >> 9, k = i & 511;
        xs[b][k] = emb[(size_t)toks[b]*HH + k];
    }
    __syncthreads();
    float acc[4];
    #pragma unroll
    for (int u = 0; u < 4; u++) acc[u] = bctx[j];
    for (int k = 0; k < HH; k += 4) {
        float w0 = Wctx[(k+0)*HH+j], w1 = Wctx[(k+1)*HH+j],
              w2 = Wctx[(k+2)*HH+j], w3 = Wctx[(k+3)*HH+j];
        #pragma unroll
        for (int u = 0; u < 4; u++) {
            int b = bq*4 + u;
            float4 hv = *reinterpret_cast<const float4*>(&xs[b][k]);
            acc[u] = fmaf(hv.x, w0, acc[u]);
            acc[u] = fmaf(hv.y, w1, acc[u]);
            acc[u] = fmaf(hv.z, w2, acc[u]);
            acc[u] = fmaf(hv.w, w3, acc[u]);
        }
    }
    #pragma unroll
    for (int u = 0; u < 4; u++) {
        int b = bq*4 + u;
        xwpre[((size_t)t*BB + b)*HH + j] = acc[u];
    }
}

// ---------------- one-time: transpose W_glob into k4-major float4 layout ----------------
// Wt4[k4g*VV + col] = { Wg[(4k4g+0)*VV+col], ..., Wg[(4k4g+3)*VV+col] }
__global__ __launch_bounds__(256) void k_tw(const float* __restrict__ Wg, float4* __restrict__ Wt4)
{
    int k4g = blockIdx.x / 125;           // 0..383
    int cb  = blockIdx.x % 125;           // 0..124
    int col = cb*256 + threadIdx.x;
    const float* w0 = Wg + (size_t)(4*k4g)*VV + col;
    float4 v;
    v.x = w0[0];
    v.y = w0[VV];
    v.z = w0[2*VV];
    v.w = w0[3*VV];
    Wt4[(size_t)k4g*VV + col] = v;
}

// ---------------- step-finish: replicate fp32 log_softmax + s*logp quantization ----------------
// (bit-identical to rounds 2-4; NCHUNK=500 guard — gmax is a pure max, bit-safe)
__device__ void finish_step(int tp, int b, int tid,
                            const int* __restrict__ s,
                            const float* __restrict__ lb,
                            const float* __restrict__ pmax,
                            const float* __restrict__ spart,
                            const float* __restrict__ bsw,
                            float* __restrict__ nll, float* __restrict__ out,
                            float* cv, int* ci, double* sdd, float* extra)
{
    // gmax over NCHUNK chunk maxes
    float v = -FLTMAX;
    if (tid < NCHUNK) v = pmax[tid*BB + b];
    cv[tid] = v; __syncthreads();
    for (int sft = 256; sft >= 1; sft >>= 1) {
        if (tid < sft) cv[tid] = fmaxf(cv[tid], cv[tid+sft]);
        __syncthreads();
    }
    float gmax = cv[0];
    __syncthreads();

    // pass A: S = sum exp(fl32(x - gmax)), fp64 Taylor (|u| small; bias-free)
    const float* Lb = lb + (size_t)b*VV;
    double sd = 0.0;
    for (int col = tid; col < VV; col += 512) {
        float d1 = Lb[col] - gmax;
        double u = (double)d1, e;
        if (u < -0.25) {
            e = exp(u);
        } else {
            e = 1.0 + u*(1.0/7.0);
            e = 1.0 + u*e*(1.0/6.0);
            e = 1.0 + u*e*(1.0/5.0);
            e = 1.0 + u*e*(1.0/4.0);
            e = 1.0 + u*e*(1.0/3.0);
            e = 1.0 + u*e*(1.0/2.0);
            e = 1.0 + u*e;
        }
        sd += e;
    }
    sdd[tid] = sd; __syncthreads();
    for (int sft = 256; sft >= 1; sft >>= 1) {
        if (tid < sft) sdd[tid] += sdd[tid+sft];
        __syncthreads();
    }
    float logS = logf((float)sdd[0]);

    // switch s = sigmoid(z), precise expf (replicates np's 1/(1+exp(-z)))
    float z = bsw[0];
    #pragma unroll
    for (int i2 = 0; i2 < 8; i2++) z += spart[b*8 + i2];
    float sF = 1.0f/(1.0f + expf(-z));
    __syncthreads();

    // pass B: quantized argmax + target capture
    int tg = s[b*LL + tp + 1];
    float best = -FLTMAX; int bidx = 0x7fffffff;
    for (int col = tid; col < VV; col += 512) {
        float d1 = Lb[col] - gmax;
        float d2 = d1 - logS;
        float pq = sF * d2;
        if (pq > best) { best = pq; bidx = col; }
        if (col == tg) extra[0] = pq;
    }
    cv[tid] = best; ci[tid] = bidx; __syncthreads();
    for (int sft = 256; sft >= 1; sft >>= 1) {
        if (tid < sft) {
            float v2 = cv[tid+sft]; int i2 = ci[tid+sft];
            if (v2 > cv[tid] || (v2 == cv[tid] && i2 < ci[tid])) { cv[tid] = v2; ci[tid] = i2; }
        }
        __syncthreads();
    }
    if (tid == 0) {
        out[1 + b*TT + tp] = (float)ci[0];
        nll[tp*BB + b] = (tg != PAD_TOK) ? -extra[0] : 0.f;
    }
    __syncthreads();
}

// ---------------- per-step kernel 1: finish prev step + attention + hid ----------------
// (bit-identical to rounds 2-4 fused version)
__global__ __launch_bounds__(512) void k_attn(
    int t, const int* __restrict__ s,
    const float* __restrict__ Whid, const float* __restrict__ bhid,
    const float* __restrict__ vw, const float* __restrict__ vb,
    const float* __restrict__ Wctx, const float* __restrict__ xwpre,
    const float* __restrict__ hs, float* __restrict__ hidg,
    const float* __restrict__ lb, const float* __restrict__ pmax,
    const float* __restrict__ spart, const float* __restrict__ bsw,
    float* __restrict__ nll, float* __restrict__ out)
{
    int b = blockIdx.x, tid = threadIdx.x;
    __shared__ float hsh[HH], qs[HH], ctxs[HH];
    __shared__ float sc[AA], at[AA];
    __shared__ float cv[512];
    __shared__ int   ci[512];
    __shared__ double sdd[512];
    __shared__ float extra[2];

    // ---- phase 0: finish step t-1 ----
    if (t > 0) {
        finish_step(t-1, b, tid, s, lb, pmax, spart, bsw, nll, out, cv, ci, sdd, extra);
    }

    // ---- phase 1: load h_prev (hs row A+t-1; t=0 -> row 31 = zeros) ----
    const float* hp = hs + ((size_t)b*HSROW + (AA + t - 1))*HH;
    for (int k = tid; k < HH; k += 512) hsh[k] = hp[k];
    __syncthreads();

    // ---- phase 2: q = h @ W_hid + b_hid ----
    {
        int j = tid;
        float acc = bhid[j];
        for (int k = 0; k < HH; k += 4) {
            float4 hv = *reinterpret_cast<const float4*>(&hsh[k]);
            acc = fmaf(hv.x, Whid[(k+0)*HH+j], acc);
            acc = fmaf(hv.y, Whid[(k+1)*HH+j], acc);
            acc = fmaf(hv.z, Whid[(k+2)*HH+j], acc);
            acc = fmaf(hv.w, Whid[(k+3)*HH+j], acc);
        }
        qs[j] = acc;
    }
    __syncthreads();

    // ---- phase 3: scores[a] = tanh(q + mem[a]) . v_w + v_b (masked) ----
    {
        int w = tid >> 6, lane = tid & 63;
        for (int r = 0; r < 4; r++) {
            int a = w + 8*r;
            const float* mem = hs + ((size_t)b*HSROW + (t + a))*HH;
            float p = 0.f;
            for (int j = lane; j < HH; j += 64) p += tanhf(qs[j] + mem[j]) * vw[j];
            for (int m = 32; m >= 1; m >>= 1) p += __shfl_xor(p, m);
            if (lane == 0) sc[a] = (a >= AA - t) ? (p + vb[0]) : -1e20f;
        }
    }
    __syncthreads();

    // ---- phase 4: softmax over 32 (wave 0) ----
    if (tid < 64) {
        float v = (tid < 32) ? sc[tid] : -FLTMAX;
        float m = v;
        for (int sh = 16; sh >= 1; sh >>= 1) m = fmaxf(m, __shfl_xor(m, sh));
        float e = (tid < 32) ? __expf(v - m) : 0.f;
        float ss = e;
        for (int sh = 16; sh >= 1; sh >>= 1) ss += __shfl_xor(ss, sh);
        if (tid < 32) at[tid] = e / ss;
    }
    __syncthreads();

    // ---- phase 5: context ----
    {
        int j = tid;
        float ctx = 0.f;
        for (int a = 0; a < AA; a++)
            ctx += at[a] * hs[((size_t)b*HSROW + (t + a))*HH + j];
        ctxs[j] = ctx;
    }
    __syncthreads();

    // ---- phase 6: hid = selu(xwpre + context @ W_ctx[512:1024]) ----
    {
        int j = tid;
        float acc = xwpre[((size_t)t*BB + b)*HH + j];
        const float* W2 = Wctx + (size_t)HH*HH;
        for (int k = 0; k < HH; k += 4) {
            float4 hv = *reinterpret_cast<const float4*>(&ctxs[k]);
            acc = fmaf(hv.x, W2[(k+0)*HH+j], acc);
            acc = fmaf(hv.y, W2[(k+1)*HH+j], acc);
            acc = fmaf(hv.z, W2[(k+2)*HH+j], acc);
            acc = fmaf(hv.w, W2[(k+3)*HH+j], acc);
        }
        const float scl = 1.0507009873554805f, al = 1.6732632423543772f;
        hidg[b*HH + j] = (acc > 0.f) ? scl*acc : scl*al*expm1f(acc);
    }
}

// ---------------- per-step kernel 2: gates + h_new/c_new + hs_buf write + zbuf fill ----------------
__global__ __launch_bounds__(256) void k_gates(
    int t, const int* __restrict__ parents,
    const float* __restrict__ Wih, const float* __restrict__ Whh,
    const float* __restrict__ blstm, const float* __restrict__ wsw,
    const float* __restrict__ hidg, float* __restrict__ hs,
    float* __restrict__ cvec, float* __restrict__ spart,
    float* __restrict__ zbuf)
{
    int bid = blockIdx.x, b = bid >> 3, hc = bid & 7, h0 = hc*64;
    int tid = threadIdx.x, g = tid >> 6, jj = tid & 63, j = h0 + jj, col = g*HH + j;
    __shared__ float hid_s[HH], h_s[HH];
    __shared__ float gsl[4][64];
    const float* hp = hs + ((size_t)b*HSROW + (AA + t - 1))*HH;
    for (int k = tid; k < HH; k += 256) { hid_s[k] = hidg[b*HH + k]; h_s[k] = hp[k]; }
    __syncthreads();
    float acc = blstm[col];
    for (int k = 0; k < HH; k += 4) {
        float4 hv = *reinterpret_cast<const float4*>(&hid_s[k]);
        acc = fmaf(hv.x, Wih[(size_t)(k+0)*2048 + col], acc);
        acc = fmaf(hv.y, Wih[(size_t)(k+1)*2048 + col], acc);
        acc = fmaf(hv.z, Wih[(size_t)(k+2)*2048 + col], acc);
        acc = fmaf(hv.w, Wih[(size_t)(k+3)*2048 + col], acc);
    }
    for (int k = 0; k < HH; k += 4) {
        float4 hv = *reinterpret_cast<const float4*>(&h_s[k]);
        acc = fmaf(hv.x, Whh[(size_t)(k+0)*2048 + col], acc);
        acc = fmaf(hv.y, Whh[(size_t)(k+1)*2048 + col], acc);
        acc = fmaf(hv.z, Whh[(size_t)(k+2)*2048 + col], acc);
        acc = fmaf(hv.w, Whh[(size_t)(k+3)*2048 + col], acc);
    }
    gsl[g][jj] = acc;
    __syncthreads();
    // h_par slice copy into zbuf (pre-update rows only: p <= t-1, and t==0 -> zeros)
    if (tid >= 64 && tid < 128) {
        int jj2 = tid - 64;
        int par = parents[t];
        int tm1 = (t - 1 > 0) ? (t - 1) : 0;
        int p = (par < 0) ? 0 : ((par > tm1) ? tm1 : par);
        float v = (t == 0) ? 0.f : hs[((size_t)b*HSROW + (AA + p))*HH + h0 + jj2];
        zbuf[(size_t)b*ZK + 2*HH + h0 + jj2] = v;
    }
    if (tid < 64) {
        float gi = gsl[0][jj], gf = gsl[1][jj], gg = gsl[2][jj], go = gsl[3][jj];
        float cp = cvec[b*HH + j];
        float cn = sigm(gf)*cp + sigm(gi)*tanhf(gg);
        float hn = sigm(go)*tanhf(cn);
        cvec[b*HH + j] = cn;
        hs[((size_t)b*HSROW + (AA + t))*HH + j] = hn;
        zbuf[(size_t)b*ZK + j] = hn;
        zbuf[(size_t)b*ZK + HH + j] = cn;
        float sp = hn*wsw[j] + cn*wsw[HH + j];
        for (int m = 32; m >= 1; m >>= 1) sp += __shfl_xor(sp, m);
        if (jj == 0) spart[b*8 + hc] = sp;
    }
}

// ---------------- per-step kernel 3 (T path): streaming GEMV with transposed W ----------------
// 500 blocks x 512 threads: cl=tid&63 (64 cols), kh=(tid>>6)&1, bq=tid>>7 -> b0=bq*4.
// Per k4 iter: ONE coalesced dwordx4 w-load + 4 scalar z-loads + 16 fma.
// Per-(col,b,kh) fmaf chains and the kh0+kh1 combine bit-identical to rounds 2-5.
__global__ __launch_bounds__(512) void k_logits_T(
    const float4* __restrict__ Wt4, const float* __restrict__ bg,
    const float* __restrict__ zbuf,
    float* __restrict__ lb, float* __restrict__ pmax)
{
    int bid = blockIdx.x, tid = threadIdx.x;
    int cl = tid & 63;
    int kh = __builtin_amdgcn_readfirstlane((tid >> 6) & 1);
    int b0 = __builtin_amdgcn_readfirstlane((tid >> 7) * 4);
    int col = bid * CHW + cl;

    __shared__ float red[4*4*64];   // [bq][u][cl]
    float acc[4];
    #pragma unroll
    for (int u = 0; u < 4; u++) acc[u] = (kh == 0) ? bg[col] : 0.f;

    for (int kc = 0; kc < 3; kc++) {
        const float* zb = zbuf + kc*512;
        const float4* wt = Wt4 + (size_t)(kc*128 + kh*64)*VV + col;
        #pragma unroll 4
        for (int k4 = 0; k4 < 64; k4++) {
            int kb = kh*256 + k4*4;
            float4 w = wt[(size_t)k4*VV];
            #pragma unroll
            for (int u = 0; u < 4; u++) {
                float4 z = *reinterpret_cast<const float4*>(&zb[(size_t)(b0+u)*ZK + kb]);
                acc[u] = fmaf(z.x, w.x, fmaf(z.y, w.y, fmaf(z.z, w.z, fmaf(z.w, w.w, acc[u]))));
            }
        }
    }

    // combine the two k-halves (accA + accB order, as rounds 2-5)
    int bq = tid >> 7;
    if (kh == 1) {
        #pragma unroll
        for (int u = 0; u < 4; u++) red[(bq*4 + u)*64 + cl] = acc[u];
    }
    __syncthreads();
    if (kh == 0) {
        #pragma unroll
        for (int u = 0; u < 4; u++) {
            float tot = acc[u] + red[(bq*4 + u)*64 + cl];
            lb[(size_t)(b0 + u)*VV + col] = tot;
            float v = tot;
            for (int m = 32; m >= 1; m >>= 1) v = fmaxf(v, __shfl_xor(v, m));
            if (cl == 0) pmax[bid*BB + b0 + u] = v;
        }
    }
}

// ---------------- per-step kernel 3 (fallback, no transpose): same structure, strided w loads ----
__global__ __launch_bounds__(512) void k_logits_F(
    const float* __restrict__ Wg, const float* __restrict__ bg,
    const float* __restrict__ zbuf,
    float* __restrict__ lb, float* __restrict__ pmax)
{
    int bid = blockIdx.x, tid = threadIdx.x;
    int cl = tid & 63;
    int kh = __builtin_amdgcn_readfirstlane((tid >> 6) & 1);
    int b0 = __builtin_amdgcn_readfirstlane((tid >> 7) * 4);
    int col = bid * CHW + cl;

    __shared__ float red[4*4*64];
    float acc[4];
    #pragma unroll
    for (int u = 0; u < 4; u++) acc[u] = (kh == 0) ? bg[col] : 0.f;

    for (int kc = 0; kc < 3; kc++) {
        const float* zb = zbuf + kc*512;
        const float* wbase = Wg + (size_t)(kc*512)*VV + col;
        #pragma unroll 4
        for (int k4 = 0; k4 < 64; k4++) {
            int kb = kh*256 + k4*4;
            const float* wr = wbase + (size_t)kb*VV;
            float w0 = wr[0], w1 = wr[VV], w2 = wr[2*VV], w3 = wr[3*VV];
            #pragma unroll
            for (int u = 0; u < 4; u++) {
                float4 z = *reinterpret_cast<const float4*>(&zb[(size_t)(b0+u)*ZK + kb]);
                acc[u] = fmaf(z.x, w0, fmaf(z.y, w1, fmaf(z.z, w2, fmaf(z.w, w3, acc[u]))));
            }
        }
    }

    int bq = tid >> 7;
    if (kh == 1) {
        #pragma unroll
        for (int u = 0; u < 4; u++) red[(bq*4 + u)*64 + cl] = acc[u];
    }
    __syncthreads();
    if (kh == 0) {
        #pragma unroll
        for (int u = 0; u < 4; u++) {
            float tot = acc[u] + red[(bq*4 + u)*64 + cl];
            lb[(size_t)(b0 + u)*VV + col] = tot;
            float v = tot;
            for (int m = 32; m >= 1; m >>= 1) v = fmaxf(v, __shfl_xor(v, m));
            if (cl == 0) pmax[bid*BB + b0 + u] = v;
        }
    }
}

// ---------------- finish last step (tp = TT-1), 16 blocks ----------------
__global__ __launch_bounds__(512) void k_fin_last(
    const int* __restrict__ s,
    const float* __restrict__ lb, const float* __restrict__ pmax,
    const float* __restrict__ spart, const float* __restrict__ bsw,
    float* __restrict__ nll, float* __restrict__ out)
{
    __shared__ float cv[512];
    __shared__ int   ci[512];
    __shared__ double sdd[512];
    __shared__ float extra[2];
    finish_step(TT-1, blockIdx.x, threadIdx.x, s, lb, pmax, spart, bsw, nll, out, cv, ci, sdd, extra);
}

// ---------------- loss ----------------
__global__ __launch_bounds__(256) void k_final_loss(
    const float* __restrict__ nll, float* __restrict__ out)
{
    __shared__ double cs2[256];
    int tid = threadIdx.x;
    double psm = 0.0;
    for (int i = tid; i < TT*BB; i += 256) psm += (double)nll[i];
    cs2[tid] = psm; __syncthreads();
    for (int sft = 128; sft >= 1; sft >>= 1) {
        if (tid < sft) cs2[tid] += cs2[tid+sft];
        __syncthreads();
    }
    if (tid == 0) out[0] = (float)(cs2[0] / (double)BB);
}

extern "C" void kernel_launch(void* const* d_in, const int* in_sizes, int n_in,
                              void* d_out, int out_size, void* d_ws, size_t ws_size,
                              hipStream_t stream)
{
    const int*   s_tok = (const int*)  d_in[0];
    const int*   par   = (const int*)  d_in[1];
    const float* emb   = (const float*)d_in[2];
    const float* Whid  = (const float*)d_in[3];
    const float* bhid  = (const float*)d_in[4];
    const float* vw    = (const float*)d_in[5];
    const float* vb    = (const float*)d_in[6];
    const float* Wctx  = (const float*)d_in[7];
    const float* bctx  = (const float*)d_in[8];
    const float* Wih   = (const float*)d_in[9];
    const float* Whh   = (const float*)d_in[10];
    const float* blstm = (const float*)d_in[11];
    const float* Wg    = (const float*)d_in[12];
    const float* bg    = (const float*)d_in[13];
    const float* wsw   = (const float*)d_in[14];
    const float* bsw   = (const float*)d_in[15];
    float* out = (float*)d_out;

    float* ws    = (float*)d_ws;
    float* hs    = ws;                     // 16*96*512 = 786432
    float* cvec  = hs    + 786432;         // 8192
    float* xwpre = cvec  + 8192;           // 63*16*512 = 516096
    float* hidg  = xwpre + 516096;         // 8192
    float* pmax  = hidg  + 8192;           // 8000
    float* spart = pmax  + 8000;           // 128
    float* nll   = spart + 128;            // 1008
    float* lb    = nll   + 1008;           // 16*32000 = 512000
    float* zbuf  = lb    + 512000;         // 16*1536 = 24576
    float* wt    = zbuf  + 24576;          // 1536*32000 = 49152000 (if ws allows)

    size_t base_floats  = 786432 + 8192 + 516096 + 8192 + 8000 + 128 + 1008 + 512000 + 24576;
    size_t need_T_bytes = (base_floats + (size_t)1536*VV) * sizeof(float);
    // align wt to 16B for float4 stores (base_floats is a multiple of 4 floats anyway)
    float4* Wt4 = (float4*)wt;
    int use_T = (ws_size >= need_T_bytes) ? 1 : 0;

    // zero hs_buf + cvec (adjacent)
    hipMemsetAsync(hs, 0, (786432 + 8192) * sizeof(float), stream);

    if (use_T) {
        hipLaunchKernelGGL(k_tw, dim3(384*125), dim3(256), 0, stream, Wg, Wt4);
    }

    hipLaunchKernelGGL(k_pre, dim3(TT*8), dim3(256), 0, stream, s_tok, emb, Wctx, bctx, xwpre);

    for (int t = 0; t < TT; t++) {
        hipLaunchKernelGGL(k_attn, dim3(BB), dim3(512), 0, stream,
            t, s_tok, Whid, bhid, vw, vb, Wctx, xwpre, hs, hidg,
            lb, pmax, spart, bsw, nll, out);
        hipLaunchKernelGGL(k_gates, dim3(128), dim3(256), 0, stream,
            t, par, Wih, Whh, blstm, wsw, hidg, hs, cvec, spart, zbuf);
        if (use_T) {
            hipLaunchKernelGGL(k_logits_T, dim3(NCHUNK), dim3(512), 0, stream,
                Wt4, bg, zbuf, lb, pmax);
        } else {
            hipLaunchKernelGGL(k_logits_F, dim3(NCHUNK), dim3(512), 0, stream,
                Wg, bg, zbuf, lb, pmax);
        }
    }

    hipLaunchKernelGGL(k_fin_last, dim3(BB), dim3(512), 0, stream,
        s_tok, lb, pmax, spart, bsw, nll, out);
    hipLaunchKernelGGL(k_final_loss, dim3(1), dim3(256), 0, stream, nll, out);
}

// Round 7
// 7242.519 us; speedup vs baseline: 2.1399x; 1.3465x over previous
//
#include <hip/hip_runtime.h>
#include <math.h>

#define BB 16
#define LL 64
#define TT 63          // L-1 steps
#define HH 512
#define AA 32          // ATTN window
#define VV 32000
#define NCHUNK 500     // V chunks for big matmul
#define CHW 64         // cols per chunk (500*64 = 32000)
#define PAD_TOK 1
#define SOS_TOK 2
#define HSROW 96       // A + L rows in hs_buf
#define ZK 1536        // z length
#define FLTMAX 3.402823466e38f

__device__ __forceinline__ float sigm(float x){ return 1.0f/(1.0f + __expf(-x)); }

// ---------------- prologue: xwpre[t][b][:] = b_ctx + emb[tok(t,b)] @ W_ctx[0:512] ----------------
__global__ __launch_bounds__(256) void k_pre(const int* __restrict__ s, const float* __restrict__ emb,
                      const float* __restrict__ Wctx, const float* __restrict__ bctx,
                      float* __restrict__ xwpre)
{
    int t = blockIdx.x >> 3;          // 0..62
    int jc = blockIdx.x & 7;          // 0..7
    int tid = threadIdx.x;
    int jj = tid & 63, bq = tid >> 6; // bq 0..3
    int j = jc*64 + jj;
    __shared__ int toks[BB];
    __shared__ float xs[BB][HH];
    if (tid < BB) {
        int b = tid;
        toks[b] = (t == 0) ? SOS_TOK : s[b*LL + (t-1)];
    }
    __syncthreads();
    for (int i = tid; i < BB*HH; i += 256) {
        int b = i >> 9, k = i & 511;
        xs[b][k] = emb[(size_t)toks[b]*HH + k];
    }
    __syncthreads();
    float acc[4];
    #pragma unroll
    for (int u = 0; u < 4; u++) acc[u] = bctx[j];
    for (int k = 0; k < HH; k += 4) {
        float w0 = Wctx[(k+0)*HH+j], w1 = Wctx[(k+1)*HH+j],
              w2 = Wctx[(k+2)*HH+j], w3 = Wctx[(k+3)*HH+j];
        #pragma unroll
        for (int u = 0; u < 4; u++) {
            int b = bq*4 + u;
            float4 hv = *reinterpret_cast<const float4*>(&xs[b][k]);
            acc[u] = fmaf(hv.x, w0, acc[u]);
            acc[u] = fmaf(hv.y, w1, acc[u]);
            acc[u] = fmaf(hv.z, w2, acc[u]);
            acc[u] = fmaf(hv.w, w3, acc[u]);
        }
    }
    #pragma unroll
    for (int u = 0; u < 4; u++) {
        int b = bq*4 + u;
        xwpre[((size_t)t*BB + b)*HH + j] = acc[u];
    }
}

// ---------------- one-time: W_glob -> column-blocked k4-major float4 layout ----------------
// Wt4b[(col>>6)*(384*64) + kg*64 + (col&63)] = { Wg[4kg+0][col], ..., Wg[4kg+3][col] }
__global__ __launch_bounds__(256) void k_tw(const float* __restrict__ Wg, float4* __restrict__ Wt4b)
{
    int kg = blockIdx.x / 125;            // 0..383
    int cb = blockIdx.x % 125;            // 0..124
    int col = cb*256 + threadIdx.x;
    const float* w0 = Wg + (size_t)(4*kg)*VV + col;
    float4 v;
    v.x = w0[0];
    v.y = w0[VV];
    v.z = w0[2*VV];
    v.w = w0[3*VV];
    Wt4b[(size_t)(col >> 6)*(384*64) + kg*64 + (col & 63)] = v;
}

// ---------------- one-time: W_ih / W_hh (512 x 2048) -> k4-major float4 ----------------
__global__ __launch_bounds__(256) void k_twl(const float* __restrict__ W, float4* __restrict__ WT)
{
    int kg = blockIdx.x >> 3;             // 0..127
    int cb = blockIdx.x & 7;              // 0..7
    int col = cb*256 + threadIdx.x;
    const float* w0 = W + (size_t)(4*kg)*2048 + col;
    float4 v;
    v.x = w0[0];
    v.y = w0[2048];
    v.z = w0[2*2048];
    v.w = w0[3*2048];
    WT[(size_t)kg*2048 + col] = v;
}

// ---------------- step-finish: replicate fp32 log_softmax + s*logp quantization ----------------
// (bit-identical to rounds 2-6)
__device__ void finish_step(int tp, int b, int tid,
                            const int* __restrict__ s,
                            const float* __restrict__ lb,
                            const float* __restrict__ pmax,
                            const float* __restrict__ spart,
                            const float* __restrict__ bsw,
                            float* __restrict__ nll, float* __restrict__ out,
                            float* cv, int* ci, double* sdd, float* extra)
{
    // gmax over NCHUNK chunk maxes
    float v = -FLTMAX;
    if (tid < NCHUNK) v = pmax[tid*BB + b];
    cv[tid] = v; __syncthreads();
    for (int sft = 256; sft >= 1; sft >>= 1) {
        if (tid < sft) cv[tid] = fmaxf(cv[tid], cv[tid+sft]);
        __syncthreads();
    }
    float gmax = cv[0];
    __syncthreads();

    // pass A: S = sum exp(fl32(x - gmax)), fp64 Taylor (|u| small; bias-free)
    const float* Lb = lb + (size_t)b*VV;
    double sd = 0.0;
    for (int col = tid; col < VV; col += 512) {
        float d1 = Lb[col] - gmax;
        double u = (double)d1, e;
        if (u < -0.25) {
            e = exp(u);
        } else {
            e = 1.0 + u*(1.0/7.0);
            e = 1.0 + u*e*(1.0/6.0);
            e = 1.0 + u*e*(1.0/5.0);
            e = 1.0 + u*e*(1.0/4.0);
            e = 1.0 + u*e*(1.0/3.0);
            e = 1.0 + u*e*(1.0/2.0);
            e = 1.0 + u*e;
        }
        sd += e;
    }
    sdd[tid] = sd; __syncthreads();
    for (int sft = 256; sft >= 1; sft >>= 1) {
        if (tid < sft) sdd[tid] += sdd[tid+sft];
        __syncthreads();
    }
    float logS = logf((float)sdd[0]);

    // switch s = sigmoid(z), precise expf (replicates np's 1/(1+exp(-z)))
    float z = bsw[0];
    #pragma unroll
    for (int i2 = 0; i2 < 8; i2++) z += spart[b*8 + i2];
    float sF = 1.0f/(1.0f + expf(-z));
    __syncthreads();

    // pass B: quantized argmax + target capture
    int tg = s[b*LL + tp + 1];
    float best = -FLTMAX; int bidx = 0x7fffffff;
    for (int col = tid; col < VV; col += 512) {
        float d1 = Lb[col] - gmax;
        float d2 = d1 - logS;
        float pq = sF * d2;
        if (pq > best) { best = pq; bidx = col; }
        if (col == tg) extra[0] = pq;
    }
    cv[tid] = best; ci[tid] = bidx; __syncthreads();
    for (int sft = 256; sft >= 1; sft >>= 1) {
        if (tid < sft) {
            float v2 = cv[tid+sft]; int i2 = ci[tid+sft];
            if (v2 > cv[tid] || (v2 == cv[tid] && i2 < ci[tid])) { cv[tid] = v2; ci[tid] = i2; }
        }
        __syncthreads();
    }
    if (tid == 0) {
        out[1 + b*TT + tp] = (float)ci[0];
        nll[tp*BB + b] = (tg != PAD_TOK) ? -extra[0] : 0.f;
    }
    __syncthreads();
}

// ---------------- deferred finishes: grid = nsteps*16 blocks ----------------
__global__ __launch_bounds__(512) void k_fin_all(
    int t0, const int* __restrict__ s,
    const float* __restrict__ lbBase, unsigned long long lbStride,
    const float* __restrict__ pmaxBase, unsigned long long pmaxStride,
    const float* __restrict__ spartAll, const float* __restrict__ bsw,
    float* __restrict__ nll, float* __restrict__ out)
{
    __shared__ float cv[512];
    __shared__ int   ci[512];
    __shared__ double sdd[512];
    __shared__ float extra[2];
    int idx = blockIdx.x >> 4;
    int tp = t0 + idx, b = blockIdx.x & 15;
    finish_step(tp, b, threadIdx.x, s,
                lbBase + (size_t)idx * lbStride,
                pmaxBase + (size_t)idx * pmaxStride,
                spartAll + (size_t)tp * 128,
                bsw, nll, out, cv, ci, sdd, extra);
}

// ---------------- per-step kernel 1: attention + hid (no finish; bit-identical phases) --------
__global__ __launch_bounds__(512) void k_attn(
    int t,
    const float* __restrict__ Whid, const float* __restrict__ bhid,
    const float* __restrict__ vw, const float* __restrict__ vb,
    const float* __restrict__ Wctx, const float* __restrict__ xwpre,
    const float* __restrict__ hs, float* __restrict__ hidg)
{
    int b = blockIdx.x, tid = threadIdx.x;
    __shared__ float hsh[HH], qs[HH], ctxs[HH];
    __shared__ float sc[AA], at[AA];

    // ---- phase 1: load h_prev (hs row A+t-1; t=0 -> row 31 = zeros) ----
    const float* hp = hs + ((size_t)b*HSROW + (AA + t - 1))*HH;
    for (int k = tid; k < HH; k += 512) hsh[k] = hp[k];
    __syncthreads();

    // ---- phase 2: q = h @ W_hid + b_hid ----
    {
        int j = tid;
        float acc = bhid[j];
        for (int k = 0; k < HH; k += 4) {
            float4 hv = *reinterpret_cast<const float4*>(&hsh[k]);
            acc = fmaf(hv.x, Whid[(k+0)*HH+j], acc);
            acc = fmaf(hv.y, Whid[(k+1)*HH+j], acc);
            acc = fmaf(hv.z, Whid[(k+2)*HH+j], acc);
            acc = fmaf(hv.w, Whid[(k+3)*HH+j], acc);
        }
        qs[j] = acc;
    }
    __syncthreads();

    // ---- phase 3: scores[a] = tanh(q + mem[a]) . v_w + v_b (masked) ----
    {
        int w = tid >> 6, lane = tid & 63;
        for (int r = 0; r < 4; r++) {
            int a = w + 8*r;
            const float* mem = hs + ((size_t)b*HSROW + (t + a))*HH;
            float p = 0.f;
            for (int j = lane; j < HH; j += 64) p += tanhf(qs[j] + mem[j]) * vw[j];
            for (int m = 32; m >= 1; m >>= 1) p += __shfl_xor(p, m);
            if (lane == 0) sc[a] = (a >= AA - t) ? (p + vb[0]) : -1e20f;
        }
    }
    __syncthreads();

    // ---- phase 4: softmax over 32 (wave 0) ----
    if (tid < 64) {
        float v = (tid < 32) ? sc[tid] : -FLTMAX;
        float m = v;
        for (int sh = 16; sh >= 1; sh >>= 1) m = fmaxf(m, __shfl_xor(m, sh));
        float e = (tid < 32) ? __expf(v - m) : 0.f;
        float ss = e;
        for (int sh = 16; sh >= 1; sh >>= 1) ss += __shfl_xor(ss, sh);
        if (tid < 32) at[tid] = e / ss;
    }
    __syncthreads();

    // ---- phase 5: context ----
    {
        int j = tid;
        float ctx = 0.f;
        for (int a = 0; a < AA; a++)
            ctx += at[a] * hs[((size_t)b*HSROW + (t + a))*HH + j];
        ctxs[j] = ctx;
    }
    __syncthreads();

    // ---- phase 6: hid = selu(xwpre + context @ W_ctx[512:1024]) ----
    {
        int j = tid;
        float acc = xwpre[((size_t)t*BB + b)*HH + j];
        const float* W2 = Wctx + (size_t)HH*HH;
        for (int k = 0; k < HH; k += 4) {
            float4 hv = *reinterpret_cast<const float4*>(&ctxs[k]);
            acc = fmaf(hv.x, W2[(k+0)*HH+j], acc);
            acc = fmaf(hv.y, W2[(k+1)*HH+j], acc);
            acc = fmaf(hv.z, W2[(k+2)*HH+j], acc);
            acc = fmaf(hv.w, W2[(k+3)*HH+j], acc);
        }
        const float scl = 1.0507009873554805f, al = 1.6732632423543772f;
        hidg[b*HH + j] = (acc > 0.f) ? scl*acc : scl*al*expm1f(acc);
    }
}

// ---------------- per-step kernel 2: gates (transposed W) + state update + zbuf fill ----------
// fmaf chains: k step 4 with w.x..w.w = rows 4k..4k+3 -> identical order to rounds 2-6.
__global__ __launch_bounds__(256) void k_gates(
    int t, const int* __restrict__ parents,
    const float4* __restrict__ WihT, const float4* __restrict__ WhhT,
    const float* __restrict__ blstm, const float* __restrict__ wsw,
    const float* __restrict__ hidg, float* __restrict__ hs,
    float* __restrict__ cvec, float* __restrict__ spart,
    float* __restrict__ zbuf)
{
    int bid = blockIdx.x, b = bid >> 3, hc = bid & 7, h0 = hc*64;
    int tid = threadIdx.x, g = tid >> 6, jj = tid & 63, j = h0 + jj, col = g*HH + j;
    __shared__ float hid_s[HH], h_s[HH];
    __shared__ float gsl[4][64];
    const float* hp = hs + ((size_t)b*HSROW + (AA + t - 1))*HH;
    for (int k = tid; k < HH; k += 256) { hid_s[k] = hidg[b*HH + k]; h_s[k] = hp[k]; }
    __syncthreads();
    float acc = blstm[col];
    #pragma unroll 8
    for (int kg = 0; kg < 128; kg++) {
        float4 w = WihT[(size_t)kg*2048 + col];
        float4 hv = *reinterpret_cast<const float4*>(&hid_s[kg*4]);
        acc = fmaf(hv.x, w.x, acc);
        acc = fmaf(hv.y, w.y, acc);
        acc = fmaf(hv.z, w.z, acc);
        acc = fmaf(hv.w, w.w, acc);
    }
    #pragma unroll 8
    for (int kg = 0; kg < 128; kg++) {
        float4 w = WhhT[(size_t)kg*2048 + col];
        float4 hv = *reinterpret_cast<const float4*>(&h_s[kg*4]);
        acc = fmaf(hv.x, w.x, acc);
        acc = fmaf(hv.y, w.y, acc);
        acc = fmaf(hv.z, w.z, acc);
        acc = fmaf(hv.w, w.w, acc);
    }
    gsl[g][jj] = acc;
    __syncthreads();
    // h_par slice copy into zbuf (pre-update rows only: p <= t-1, and t==0 -> zeros)
    if (tid >= 64 && tid < 128) {
        int jj2 = tid - 64;
        int par = parents[t];
        int tm1 = (t - 1 > 0) ? (t - 1) : 0;
        int p = (par < 0) ? 0 : ((par > tm1) ? tm1 : par);
        float v = (t == 0) ? 0.f : hs[((size_t)b*HSROW + (AA + p))*HH + h0 + jj2];
        zbuf[(size_t)b*ZK + 2*HH + h0 + jj2] = v;
    }
    if (tid < 64) {
        float gi = gsl[0][jj], gf = gsl[1][jj], gg = gsl[2][jj], go = gsl[3][jj];
        float cp = cvec[b*HH + j];
        float cn = sigm(gf)*cp + sigm(gi)*tanhf(gg);
        float hn = sigm(go)*tanhf(cn);
        cvec[b*HH + j] = cn;
        hs[((size_t)b*HSROW + (AA + t))*HH + j] = hn;
        zbuf[(size_t)b*ZK + j] = hn;
        zbuf[(size_t)b*ZK + HH + j] = cn;
        float sp = hn*wsw[j] + cn*wsw[HH + j];
        for (int m = 32; m >= 1; m >>= 1) sp += __shfl_xor(sp, m);
        if (jj == 0) spart[b*8 + hc] = sp;
    }
}

// ---------------- per-step kernel 3 (T path): streaming GEMV, blocked-contiguous W ----------------
__global__ __launch_bounds__(512) void k_logits_T(
    const float4* __restrict__ Wt4b, const float* __restrict__ bg,
    const float* __restrict__ zbuf,
    float* __restrict__ lb, float* __restrict__ pmax)
{
    int bid = blockIdx.x, tid = threadIdx.x;
    int cl = tid & 63;
    int kh = __builtin_amdgcn_readfirstlane((tid >> 6) & 1);
    int b0 = __builtin_amdgcn_readfirstlane((tid >> 7) * 4);
    int col = bid * CHW + cl;

    __shared__ float red[4*4*64];   // [bq][u][cl]
    float acc[4];
    #pragma unroll
    for (int u = 0; u < 4; u++) acc[u] = (kh == 0) ? bg[col] : 0.f;

    const float4* wblk = Wt4b + (size_t)bid * (384*64);
    for (int kc = 0; kc < 3; kc++) {
        const float* zb = zbuf + kc*512;
        const float4* wt = wblk + (kc*128 + kh*64)*64 + cl;
        #pragma unroll 8
        for (int k4 = 0; k4 < 64; k4++) {
            int kb = kh*256 + k4*4;
            float4 w = wt[k4*64];
            #pragma unroll
            for (int u = 0; u < 4; u++) {
                float4 z = *reinterpret_cast<const float4*>(&zb[(size_t)(b0+u)*ZK + kb]);
                acc[u] = fmaf(z.x, w.x, fmaf(z.y, w.y, fmaf(z.z, w.z, fmaf(z.w, w.w, acc[u]))));
            }
        }
    }

    // combine the two k-halves (accA + accB order, as rounds 2-6)
    int bq = tid >> 7;
    if (kh == 1) {
        #pragma unroll
        for (int u = 0; u < 4; u++) red[(bq*4 + u)*64 + cl] = acc[u];
    }
    __syncthreads();
    if (kh == 0) {
        #pragma unroll
        for (int u = 0; u < 4; u++) {
            float tot = acc[u] + red[(bq*4 + u)*64 + cl];
            lb[(size_t)(b0 + u)*VV + col] = tot;
            float v = tot;
            for (int m = 32; m >= 1; m >>= 1) v = fmaxf(v, __shfl_xor(v, m));
            if (cl == 0) pmax[bid*BB + b0 + u] = v;
        }
    }
}

// ---------------- per-step kernel 3 (fallback, untransposed W) ----------------
__global__ __launch_bounds__(512) void k_logits_F(
    const float* __restrict__ Wg, const float* __restrict__ bg,
    const float* __restrict__ zbuf,
    float* __restrict__ lb, float* __restrict__ pmax)
{
    int bid = blockIdx.x, tid = threadIdx.x;
    int cl = tid & 63;
    int kh = __builtin_amdgcn_readfirstlane((tid >> 6) & 1);
    int b0 = __builtin_amdgcn_readfirstlane((tid >> 7) * 4);
    int col = bid * CHW + cl;

    __shared__ float red[4*4*64];
    float acc[4];
    #pragma unroll
    for (int u = 0; u < 4; u++) acc[u] = (kh == 0) ? bg[col] : 0.f;

    for (int kc = 0; kc < 3; kc++) {
        const float* zb = zbuf + kc*512;
        const float* wbase = Wg + (size_t)(kc*512)*VV + col;
        #pragma unroll 4
        for (int k4 = 0; k4 < 64; k4++) {
            int kb = kh*256 + k4*4;
            const float* wr = wbase + (size_t)kb*VV;
            float w0 = wr[0], w1 = wr[VV], w2 = wr[2*VV], w3 = wr[3*VV];
            #pragma unroll
            for (int u = 0; u < 4; u++) {
                float4 z = *reinterpret_cast<const float4*>(&zb[(size_t)(b0+u)*ZK + kb]);
                acc[u] = fmaf(z.x, w0, fmaf(z.y, w1, fmaf(z.z, w2, fmaf(z.w, w3, acc[u]))));
            }
        }
    }

    int bq = tid >> 7;
    if (kh == 1) {
        #pragma unroll
        for (int u = 0; u < 4; u++) red[(bq*4 + u)*64 + cl] = acc[u];
    }
    __syncthreads();
    if (kh == 0) {
        #pragma unroll
        for (int u = 0; u < 4; u++) {
            float tot = acc[u] + red[(bq*4 + u)*64 + cl];
            lb[(size_t)(b0 + u)*VV + col] = tot;
            float v = tot;
            for (int m = 32; m >= 1; m >>= 1) v = fmaxf(v, __shfl_xor(v, m));
            if (cl == 0) pmax[bid*BB + b0 + u] = v;
        }
    }
}

// ---------------- loss ----------------
__global__ __launch_bounds__(256) void k_final_loss(
    const float* __restrict__ nll, float* __restrict__ out)
{
    __shared__ double cs2[256];
    int tid = threadIdx.x;
    double psm = 0.0;
    for (int i = tid; i < TT*BB; i += 256) psm += (double)nll[i];
    cs2[tid] = psm; __syncthreads();
    for (int sft = 128; sft >= 1; sft >>= 1) {
        if (tid < sft) cs2[tid] += cs2[tid+sft];
        __syncthreads();
    }
    if (tid == 0) out[0] = (float)(cs2[0] / (double)BB);
}

extern "C" void kernel_launch(void* const* d_in, const int* in_sizes, int n_in,
                              void* d_out, int out_size, void* d_ws, size_t ws_size,
                              hipStream_t stream)
{
    const int*   s_tok = (const int*)  d_in[0];
    const int*   par   = (const int*)  d_in[1];
    const float* emb   = (const float*)d_in[2];
    const float* Whid  = (const float*)d_in[3];
    const float* bhid  = (const float*)d_in[4];
    const float* vw    = (const float*)d_in[5];
    const float* vb    = (const float*)d_in[6];
    const float* Wctx  = (const float*)d_in[7];
    const float* bctx  = (const float*)d_in[8];
    const float* Wih   = (const float*)d_in[9];
    const float* Whh   = (const float*)d_in[10];
    const float* blstm = (const float*)d_in[11];
    const float* Wg    = (const float*)d_in[12];
    const float* bg    = (const float*)d_in[13];
    const float* wsw   = (const float*)d_in[14];
    const float* bsw   = (const float*)d_in[15];
    float* out = (float*)d_out;

    size_t ws_f = ws_size / sizeof(float);
    // mode 2 (full): deferred finish + blocked Wt + transposed lstm
    // mode 1 (mid) : per-step finish + blocked Wt + transposed lstm
    // mode 0 (low) : per-step finish + untransposed Wg + transposed lstm
    const size_t base_f = 786432 + 8192 + 516096 + 8192;             // hs,cvec,xwpre,hidg
    const size_t tail_f = 8064 + 1008 + 24576 + 2*1048576;           // spartAll,nll,zbuf,WihT,WhhT
    const size_t full_f = base_f + tail_f + (size_t)63*8000 + (size_t)63*512000 + 49152000;
    const size_t mid_f  = base_f + tail_f + 8000 + 512000 + 49152000;
    int mode = (ws_f >= full_f) ? 2 : ((ws_f >= mid_f) ? 1 : 0);

    float* ws = (float*)d_ws;
    size_t off = 0;
    float* hs      = ws + off; off += 786432;
    float* cvec    = ws + off; off += 8192;
    float* xwpre   = ws + off; off += 516096;
    float* hidg    = ws + off; off += 8192;
    float* pmaxAll = ws + off; off += (mode == 2) ? (size_t)63*8000 : 8000;
    float* spartAll= ws + off; off += 8064;
    float* nll     = ws + off; off += 1008;
    float* zbuf    = ws + off; off += 24576;
    float* lbAll   = ws + off; off += (mode == 2) ? (size_t)63*512000 : 512000;
    float4* WihT   = (float4*)(ws + off); off += 1048576;
    float4* WhhT   = (float4*)(ws + off); off += 1048576;
    float4* Wt4b   = (float4*)(ws + off); // only used in mode>=1

    size_t lbStride   = (mode == 2) ? 512000 : 0;
    size_t pmaxStride = (mode == 2) ? 8000 : 0;

    // zero hs_buf + cvec (adjacent)
    hipMemsetAsync(hs, 0, (786432 + 8192) * sizeof(float), stream);

    hipLaunchKernelGGL(k_twl, dim3(1024), dim3(256), 0, stream, Wih, WihT);
    hipLaunchKernelGGL(k_twl, dim3(1024), dim3(256), 0, stream, Whh, WhhT);
    if (mode >= 1) {
        hipLaunchKernelGGL(k_tw, dim3(384*125), dim3(256), 0, stream, Wg, Wt4b);
    }
    hipLaunchKernelGGL(k_pre, dim3(TT*8), dim3(256), 0, stream, s_tok, emb, Wctx, bctx, xwpre);

    for (int t = 0; t < TT; t++) {
        hipLaunchKernelGGL(k_attn, dim3(BB), dim3(512), 0, stream,
            t, Whid, bhid, vw, vb, Wctx, xwpre, hs, hidg);
        hipLaunchKernelGGL(k_gates, dim3(128), dim3(256), 0, stream,
            t, par, WihT, WhhT, blstm, wsw, hidg, hs, cvec, spartAll + (size_t)t*128, zbuf);
        float* lb_t   = lbAll  + (size_t)t * lbStride;
        float* pmax_t = pmaxAll+ (size_t)t * pmaxStride;
        if (mode >= 1) {
            hipLaunchKernelGGL(k_logits_T, dim3(NCHUNK), dim3(512), 0, stream,
                Wt4b, bg, zbuf, lb_t, pmax_t);
        } else {
            hipLaunchKernelGGL(k_logits_F, dim3(NCHUNK), dim3(512), 0, stream,
                Wg, bg, zbuf, lb_t, pmax_t);
        }
        if (mode < 2) {
            hipLaunchKernelGGL(k_fin_all, dim3(BB), dim3(512), 0, stream,
                t, s_tok, lb_t, (unsigned long long)0, pmax_t, (unsigned long long)0,
                spartAll, bsw, nll, out);
        }
    }

    if (mode == 2) {
        hipLaunchKernelGGL(k_fin_all, dim3(TT*BB), dim3(512), 0, stream,
            0, s_tok, lbAll, (unsigned long long)lbStride,
            pmaxAll, (unsigned long long)pmaxStride,
            spartAll, bsw, nll, out);
    }
    hipLaunchKernelGGL(k_final_loss, dim3(1), dim3(256), 0, stream, nll, out);
}